// Round 5
// baseline (378.048 us; speedup 1.0000x reference)
//
#include <hip/hip_runtime.h>
#include <math.h>

#define N_PTS   8192
#define NBATCH  4
#define NQ      (N_PTS*NBATCH)   // 32768
#define GFN     100
#define KNN     10
#define NSPLIT  2
#define SPLITL  (N_PTS/NSPLIT)   // 4096
#define MBLK    64               // points per mlp1 block
#define CHK     25               // channels per wave (4 waves * 25 = 100)

__device__ __forceinline__ float med3f(float a, float b, float c){
  return __builtin_amdgcn_fmed3f(a, b, c);
}

// sorted insert of d into ascending m[0..9], dropping the largest.
// no-op when d >= m[9].
__device__ __forceinline__ void insert10(float (&m)[KNN], float d){
  #pragma unroll
  for (int k = KNN-1; k > 0; k--) m[k] = med3f(d, m[k-1], m[k]);
  m[0] = fminf(m[0], d);
}

// ---------------- K1: KNN top-10 distances, 2-way split over j ----------------
// Long 4096-pt scans keep the top-10 threshold tight -> wave-level insert branch
// taken only ~45% of iterations. 8-deep register prefetch hides LDS latency at
// 1 wave/SIMD occupancy.
__global__ __launch_bounds__(256) void knn_kernel(const float* __restrict__ x,
                                                  float* __restrict__ cand,
                                                  float* __restrict__ pool){
  __shared__ float4 tile[SPLITL];   // 64 KB: (x,y,z,sq)
  const int t  = threadIdx.x;
  const int qb = blockIdx.x;        // 0..127
  const int s  = blockIdx.y;        // 0..1
  const int q  = qb * 256 + t;
  const int b  = q >> 13;
  const float* xb = x + (size_t)b * N_PTS * 3;

  if (qb == 0 && s == 0){
    for (int i = t; i < NBATCH*GFN; i += 256) pool[i] = 0.0f;
  }

  // stage 4096 points: each thread loads 12 float4 (48 floats = 16 points)
  {
    const float4* src = reinterpret_cast<const float4*>(xb + (size_t)s * SPLITL * 3);
    float f[48];
    #pragma unroll
    for (int k = 0; k < 12; k++){
      float4 v = src[t*12 + k];
      f[4*k+0] = v.x; f[4*k+1] = v.y; f[4*k+2] = v.z; f[4*k+3] = v.w;
    }
    #pragma unroll
    for (int p = 0; p < 16; p++){
      float px = f[3*p+0], py = f[3*p+1], pz = f[3*p+2];
      float sq = fmaf(pz, pz, fmaf(py, py, px*px));
      tile[t*16 + p] = make_float4(px, py, pz, sq);
    }
  }
  __syncthreads();

  const float xi = x[(size_t)q*3+0], yi = x[(size_t)q*3+1], zi = x[(size_t)q*3+2];
  const float sqi = fmaf(zi, zi, fmaf(yi, yi, xi*xi));

  float m[KNN];
  #pragma unroll
  for (int k = 0; k < KNN; k++) m[k] = INFINITY;

  float4 buf[8];
  #pragma unroll
  for (int u = 0; u < 8; u++) buf[u] = tile[u];

  for (int j0 = 0; j0 < SPLITL; j0 += 8){
    float4 nxt[8];
    const int jn = (j0+8 < SPLITL) ? (j0+8) : 0;   // wrap: last prefetch unused
    #pragma unroll
    for (int u = 0; u < 8; u++) nxt[u] = tile[jn + u];
    #pragma unroll
    for (int u = 0; u < 8; u++){
      float4 p = buf[u];
      float dot = fmaf(zi, p.z, fmaf(yi, p.y, xi*p.x));
      float d   = fmaf(-2.0f, dot, sqi + p.w);   // exact: -2*dot is exponent shift
      if (__any(d < m[KNN-1])) insert10(m, d);   // wave-coherent guard
    }
    #pragma unroll
    for (int u = 0; u < 8; u++) buf[u] = nxt[u];
  }

  #pragma unroll
  for (int k = 0; k < KNN; k++) cand[(size_t)(s*KNN + k)*NQ + q] = m[k];
}

// ------------- K2: merge, conv1 (13->20->100), conv2 (100->100) + pool -------------
// 256 threads = 4 waves; block owns 64 points (lane = point). Wave g computes
// channels [g*25, g*25+25). All register indices compile-time; weight addresses
// wave-uniform -> SGPR s_load. unroll 2 keeps <=50 weight SGPRs in flight.
__global__ __launch_bounds__(256) void mlp1_kernel(
    const float* __restrict__ x,   const float* __restrict__ cand,
    const float* __restrict__ w1a, const float* __restrict__ b1a,
    const float* __restrict__ w1b, const float* __restrict__ b1b,
    const float* __restrict__ w2,  const float* __restrict__ b2,
    float* __restrict__ x1t, float* __restrict__ pool){
  __shared__ float t20s[MBLK*21];    // 5.4 KB
  __shared__ float x1s[MBLK*101];    // 25.9 KB
  const int t = threadIdx.x;
  const int p = t & 63;
  const int g = __builtin_amdgcn_readfirstlane(t >> 6);  // 0..3
  const int q0 = blockIdx.x * MBLK;
  const int q  = q0 + p;
  const int b  = q0 >> 13;

  // ---- phase A: all 4 waves merge (redundantly) + each computes 5 of 20 t20 ----
  {
    float m[KNN];
    #pragma unroll
    for (int k = 0; k < KNN; k++) m[k] = INFINITY;
    #pragma unroll
    for (int i = 0; i < NSPLIT*KNN; i++) insert10(m, cand[(size_t)i*NQ + q]);

    float h[13];
    h[0] = x[(size_t)q*3+0]; h[1] = x[(size_t)q*3+1]; h[2] = x[(size_t)q*3+2];
    #pragma unroll
    for (int k = 0; k < KNN; k++) h[3+k] = m[k];

    float a[5];
    #pragma unroll
    for (int j = 0; j < 5; j++) a[j] = b1a[g*5+j];
    #pragma unroll
    for (int c = 0; c < 13; c++){
      float hv = h[c];
      #pragma unroll
      for (int j = 0; j < 5; j++) a[j] = fmaf(hv, w1a[c*20 + g*5 + j], a[j]);
    }
    #pragma unroll
    for (int j = 0; j < 5; j++) t20s[p*21 + g*5 + j] = fmaxf(a[j], 0.0f);
  }
  __syncthreads();

  const int o0 = g * CHK;
  float acc[CHK];

  // ---- phase B: x1 = relu(t20 @ w1b + b1b) ----
  #pragma unroll
  for (int k = 0; k < CHK; k++) acc[k] = b1b[o0+k];
  #pragma unroll 2
  for (int c = 0; c < 20; c++){
    float tv = t20s[p*21 + c];
    #pragma unroll
    for (int k = 0; k < CHK; k++) acc[k] = fmaf(tv, w1b[c*GFN + o0 + k], acc[k]);
  }
  #pragma unroll
  for (int k = 0; k < CHK; k++){
    float v = fmaxf(acc[k], 0.0f);
    x1s[p*101 + o0 + k] = v;
    x1t[(size_t)(o0+k)*NQ + q] = v;    // coalesced
  }
  __syncthreads();

  // ---- phase C: x2 = relu(x1 @ w2 + b2), then pool reduce ----
  #pragma unroll
  for (int k = 0; k < CHK; k++) acc[k] = b2[o0+k];
  #pragma unroll 2
  for (int c = 0; c < GFN; c++){
    float xv = x1s[p*101 + c];
    #pragma unroll
    for (int k = 0; k < CHK; k++) acc[k] = fmaf(xv, w2[c*GFN + o0 + k], acc[k]);
  }
  #pragma unroll
  for (int k = 0; k < CHK; k++){
    float v = fmaxf(acc[k], 0.0f);
    #pragma unroll
    for (int off = 1; off < 64; off <<= 1) v += __shfl_xor(v, off);
    if (p == 0) atomicAdd(&pool[b*GFN + o0 + k], v);
  }
}

// ---------------- K3: head (200->20->10->2) + log_softmax ----------------
__global__ __launch_bounds__(128) void head_kernel(
    const float* __restrict__ x1t, const float* __restrict__ pool,
    const float* __restrict__ w3a, const float* __restrict__ b3a,
    const float* __restrict__ w3b, const float* __restrict__ b3b,
    const float* __restrict__ w3c, const float* __restrict__ b3c,
    float* __restrict__ out){
  __shared__ float poolm[GFN];
  __shared__ float poolpart[20];
  const int t = threadIdx.x;
  const int q = blockIdx.x * 128 + t;
  const int b = q >> 13;

  if (t < GFN) poolm[t] = pool[b*GFN+t] * (1.0f / (float)N_PTS);
  __syncthreads();
  if (t < 20){
    float a = b3a[t];
    for (int c = 0; c < GFN; c++) a = fmaf(poolm[c], w3a[(GFN+c)*20+t], a);
    poolpart[t] = a;
  }
  __syncthreads();

  float acc[20];
  #pragma unroll
  for (int o = 0; o < 20; o++) acc[o] = 0.0f;
  #pragma unroll 8
  for (int c = 0; c < GFN; c++){
    float xv = x1t[(size_t)c*NQ + q];
    #pragma unroll
    for (int o = 0; o < 20; o++) acc[o] = fmaf(xv, w3a[c*20+o], acc[o]);
  }
  float o1[20];
  #pragma unroll
  for (int o = 0; o < 20; o++) o1[o] = fmaxf(acc[o] + poolpart[o], 0.0f);

  float o2[10];
  #pragma unroll
  for (int o = 0; o < 10; o++){
    float a = b3b[o];
    #pragma unroll
    for (int c = 0; c < 20; c++) a = fmaf(o1[c], w3b[c*10+o], a);
    o2[o] = fmaxf(a, 0.0f);
  }
  float e0 = b3c[0], e1 = b3c[1];
  #pragma unroll
  for (int c = 0; c < 10; c++){
    e0 = fmaf(o2[c], w3c[c*2+0], e0);
    e1 = fmaf(o2[c], w3c[c*2+1], e1);
  }
  float mx = fmaxf(e0, e1);
  float a0 = e0 - mx, a1 = e1 - mx;
  float lse = logf(expf(a0) + expf(a1));
  float2 r; r.x = a0 - lse; r.y = a1 - lse;
  *reinterpret_cast<float2*>(out + (size_t)q*2) = r;
}

extern "C" void kernel_launch(void* const* d_in, const int* in_sizes, int n_in,
                              void* d_out, int out_size, void* d_ws, size_t ws_size,
                              hipStream_t stream) {
  const float* x   = (const float*)d_in[0];
  const float* w1a = (const float*)d_in[1];
  const float* b1a = (const float*)d_in[2];
  const float* w1b = (const float*)d_in[3];
  const float* b1b = (const float*)d_in[4];
  const float* w2  = (const float*)d_in[5];
  const float* b2  = (const float*)d_in[6];
  const float* w3a = (const float*)d_in[7];
  const float* b3a = (const float*)d_in[8];
  const float* w3b = (const float*)d_in[9];
  const float* b3b = (const float*)d_in[10];
  const float* w3c = (const float*)d_in[11];
  const float* b3c = (const float*)d_in[12];
  float* out = (float*)d_out;

  char* ws = (char*)d_ws;
  float* cand = (float*)ws;                                        // NSPLIT*KNN*NQ fp32 (2.6 MB)
  float* x1t  = (float*)(ws + (size_t)NQ*NSPLIT*KNN*4);            // GFN*NQ fp32 (13.1 MB)
  float* pool = (float*)(ws + (size_t)NQ*NSPLIT*KNN*4
                            + (size_t)GFN*NQ*4);                   // NBATCH*GFN fp32

  knn_kernel<<<dim3(NQ/256, NSPLIT), 256, 0, stream>>>(x, cand, pool);
  mlp1_kernel<<<NQ/MBLK, 256, 0, stream>>>(x, cand, w1a, b1a, w1b, b1b, w2, b2, x1t, pool);
  head_kernel<<<NQ/128, 128, 0, stream>>>(x1t, pool, w3a, b3a, w3b, b3b, w3c, b3c, out);
}

// Round 6
// 292.869 us; speedup vs baseline: 1.2908x; 1.2908x over previous
//
#include <hip/hip_runtime.h>
#include <math.h>

#define N_PTS   8192
#define NBATCH  4
#define NQ      (N_PTS*NBATCH)   // 32768
#define GFN     100
#define KNN     10
#define NSPLIT  16
#define SPLITL  (N_PTS/NSPLIT)   // 512
#define QPL     4                // queries per lane in knn
#define MBLK    128              // points per mlp1 block

__device__ __forceinline__ float med3f(float a, float b, float c){
  return __builtin_amdgcn_fmed3f(a, b, c);
}

// sorted insert of d into ascending m[0..9], dropping the largest.
// each med3 reads pre-insert values (descending k) -> all independent; no-op if d>=m[9].
__device__ __forceinline__ void insert10(float (&m)[KNN], float d){
  #pragma unroll
  for (int k = KNN-1; k > 0; k--) m[k] = med3f(d, m[k-1], m[k]);
  m[0] = fminf(m[0], d);
}

// ---------------- K1: KNN top-10, 16-way split, 4 queries/lane ----------------
// One wave-uniform ds_read_b128 per j feeds 4 query-inserts -> VALU-bound, not
// LDS-issue-bound (R4 was 1 read : 1 insert = 12 cyc LDS vs 8 cyc VALU per CU).
__global__ __launch_bounds__(256) void knn_kernel(const float* __restrict__ x,
                                                  float* __restrict__ cand,
                                                  float* __restrict__ pool){
  __shared__ float4 tile[SPLITL];   // 8 KB
  const int t   = threadIdx.x;
  const int w   = t >> 6;           // wave 0..3
  const int p   = t & 63;
  const int s   = blockIdx.y;       // 0..15
  const int qb0 = blockIdx.x * 1024;   // block covers 1024 queries (one batch slice)
  const int b   = qb0 >> 13;
  const float* xb = x + (size_t)b * N_PTS * 3;

  if (blockIdx.x == 0 && s == 0){
    for (int i = t; i < NBATCH*GFN; i += 256) pool[i] = 0.0f;
  }

  // stage 512 points, thread t writes points {t, t+256} (lane-consecutive, conflict-free)
  #pragma unroll
  for (int k = 0; k < 2; k++){
    const int j = t + 256*k;
    const float* ps = xb + (size_t)(s*SPLITL + j)*3;
    float px = ps[0], py = ps[1], pz = ps[2];
    tile[j] = make_float4(px, py, pz, fmaf(pz, pz, fmaf(py, py, px*px)));
  }
  __syncthreads();

  // 4 queries per lane: q = qb0 + w*256 + u*64 + p
  float qx[QPL], qy[QPL], qz[QPL], qs[QPL];
  #pragma unroll
  for (int u = 0; u < QPL; u++){
    const int q = qb0 + w*256 + u*64 + p;
    qx[u] = x[(size_t)q*3+0];
    qy[u] = x[(size_t)q*3+1];
    qz[u] = x[(size_t)q*3+2];
    qs[u] = fmaf(qz[u], qz[u], fmaf(qy[u], qy[u], qx[u]*qx[u]));
  }

  float m[QPL][KNN];
  #pragma unroll
  for (int u = 0; u < QPL; u++)
    #pragma unroll
    for (int k = 0; k < KNN; k++) m[u][k] = INFINITY;

  #pragma unroll 4
  for (int j = 0; j < SPLITL; j++){
    float4 pt = tile[j];
    #pragma unroll
    for (int u = 0; u < QPL; u++){
      float dot = fmaf(qz[u], pt.z, fmaf(qy[u], pt.y, qx[u]*pt.x));
      float d   = fmaf(-2.0f, dot, qs[u] + pt.w);   // same rounding as R4 (passed)
      insert10(m[u], d);
    }
  }

  #pragma unroll
  for (int u = 0; u < QPL; u++){
    const int q = qb0 + w*256 + u*64 + p;
    #pragma unroll
    for (int k = 0; k < KNN; k++) cand[(size_t)(s*KNN + k)*NQ + q] = m[u][k];
  }
}

// ------------- K2: merge, conv1 (13->20->100), conv2 (100->100) + pool -------------
// 512 threads = 8 waves; block owns 128 points. Wave g: point-half g>>2, channel
// chunk (g&3)*25. Weight loads wave-uniform, double-buffered in statically-indexed
// arrays (<=50 uniform values in flight), unroll-1 c-loop -> no SGPR blowup/scratch.
__global__ __launch_bounds__(512) void mlp1_kernel(
    const float* __restrict__ x,   const float* __restrict__ cand,
    const float* __restrict__ w1a, const float* __restrict__ b1a,
    const float* __restrict__ w1b, const float* __restrict__ b1b,
    const float* __restrict__ w2,  const float* __restrict__ b2,
    float* __restrict__ x1r, float* __restrict__ pool){
  __shared__ float t20s[MBLK*21];    // 10.75 KB
  __shared__ float x1s[MBLK*101];    // 51.7 KB
  const int t = threadIdx.x;
  const int p = t & 63;
  const int g = __builtin_amdgcn_readfirstlane(t >> 6);  // 0..7
  const int q0 = blockIdx.x * MBLK;
  const int b  = q0 >> 13;

  // ---- phase A: waves 0,1 do the front-end (merge + 13->20) for 64 points each ----
  if (g < 2){
    const int pr = g*64 + p;
    const int q  = q0 + pr;
    float m[KNN];
    #pragma unroll
    for (int k = 0; k < KNN; k++) m[k] = INFINITY;
    #pragma unroll 4
    for (int i = 0; i < NSPLIT*KNN; i++) insert10(m, cand[(size_t)i*NQ + q]);

    float h[13];
    h[0] = x[(size_t)q*3+0]; h[1] = x[(size_t)q*3+1]; h[2] = x[(size_t)q*3+2];
    #pragma unroll
    for (int k = 0; k < KNN; k++) h[3+k] = m[k];

    float a[20];
    #pragma unroll
    for (int o = 0; o < 20; o++) a[o] = b1a[o];
    #pragma unroll
    for (int c = 0; c < 13; c++){
      float hv = h[c];
      #pragma unroll
      for (int o = 0; o < 20; o++) a[o] = fmaf(hv, w1a[c*20+o], a[o]);
    }
    #pragma unroll
    for (int o = 0; o < 20; o++) t20s[pr*21 + o] = fmaxf(a[o], 0.0f);
  }
  __syncthreads();

  const int half = g >> 2;           // 0/1 (uniform)
  const int ph   = half*64 + p;      // point row in block
  const int q    = q0 + ph;
  const int o0   = (g & 3) * 25;     // channel chunk base (uniform)

  float acc[25];

  // ---- phase B: x1 = relu(t20 @ w1b + b1b) ----
  #pragma unroll
  for (int k = 0; k < 25; k++) acc[k] = b1b[o0+k];
  #pragma unroll 1
  for (int c = 0; c < 20; c++){
    float tv = t20s[ph*21 + c];
    #pragma unroll
    for (int k = 0; k < 25; k++) acc[k] = fmaf(tv, w1b[c*GFN + o0 + k], acc[k]);
  }
  #pragma unroll
  for (int k = 0; k < 25; k++){
    float v = fmaxf(acc[k], 0.0f);
    x1s[ph*101 + o0 + k] = v;
    x1r[(size_t)q*GFN + o0 + k] = v;   // row-major for head
  }
  __syncthreads();

  // ---- phase C: x2 = relu(x1 @ w2 + b2), double-buffered weights ----
  float wA[25], wB[25];
  #pragma unroll
  for (int k = 0; k < 25; k++) acc[k] = b2[o0+k];
  #pragma unroll
  for (int k = 0; k < 25; k++) wA[k] = w2[o0 + k];          // c=0
  #pragma unroll 1
  for (int c = 0; c < GFN; c += 2){
    #pragma unroll
    for (int k = 0; k < 25; k++) wB[k] = w2[(c+1)*GFN + o0 + k];
    float xv = x1s[ph*101 + c];
    #pragma unroll
    for (int k = 0; k < 25; k++) acc[k] = fmaf(xv, wA[k], acc[k]);
    if (c + 2 < GFN){
      #pragma unroll
      for (int k = 0; k < 25; k++) wA[k] = w2[(c+2)*GFN + o0 + k];
    }
    xv = x1s[ph*101 + c + 1];
    #pragma unroll
    for (int k = 0; k < 25; k++) acc[k] = fmaf(xv, wB[k], acc[k]);
  }

  #pragma unroll
  for (int k = 0; k < 25; k++){
    float v = fmaxf(acc[k], 0.0f);
    #pragma unroll
    for (int off = 1; off < 64; off <<= 1) v += __shfl_xor(v, off);
    if (p == 0) atomicAdd(&pool[b*GFN + o0 + k], v);
  }
}

// ---------------- K3: head (200->20->10->2) + log_softmax ----------------
// x1 rows read contiguously as float4 (25 VMEM/thread).
__global__ __launch_bounds__(128) void head_kernel(
    const float* __restrict__ x1r, const float* __restrict__ pool,
    const float* __restrict__ w3a, const float* __restrict__ b3a,
    const float* __restrict__ w3b, const float* __restrict__ b3b,
    const float* __restrict__ w3c, const float* __restrict__ b3c,
    float* __restrict__ out){
  __shared__ float poolm[GFN];
  __shared__ float poolpart[20];
  const int t = threadIdx.x;
  const int q = blockIdx.x * 128 + t;
  const int b = q >> 13;

  if (t < GFN) poolm[t] = pool[b*GFN+t] * (1.0f / (float)N_PTS);
  __syncthreads();
  if (t < 20){
    float a = b3a[t];
    for (int c = 0; c < GFN; c++) a = fmaf(poolm[c], w3a[(GFN+c)*20+t], a);
    poolpart[t] = a;
  }
  __syncthreads();

  float acc[20];
  #pragma unroll
  for (int o = 0; o < 20; o++) acc[o] = 0.0f;
  const float4* xr = reinterpret_cast<const float4*>(x1r + (size_t)q*GFN);
  #pragma unroll 5
  for (int c4 = 0; c4 < 25; c4++){
    float4 v = xr[c4];
    const float* wr = w3a + c4*4*20;
    #pragma unroll
    for (int o = 0; o < 20; o++) acc[o] = fmaf(v.x, wr[o],    acc[o]);
    #pragma unroll
    for (int o = 0; o < 20; o++) acc[o] = fmaf(v.y, wr[20+o], acc[o]);
    #pragma unroll
    for (int o = 0; o < 20; o++) acc[o] = fmaf(v.z, wr[40+o], acc[o]);
    #pragma unroll
    for (int o = 0; o < 20; o++) acc[o] = fmaf(v.w, wr[60+o], acc[o]);
  }
  float o1[20];
  #pragma unroll
  for (int o = 0; o < 20; o++) o1[o] = fmaxf(acc[o] + poolpart[o], 0.0f);

  float o2[10];
  #pragma unroll
  for (int o = 0; o < 10; o++){
    float a = b3b[o];
    #pragma unroll
    for (int c = 0; c < 20; c++) a = fmaf(o1[c], w3b[c*10+o], a);
    o2[o] = fmaxf(a, 0.0f);
  }
  float e0 = b3c[0], e1 = b3c[1];
  #pragma unroll
  for (int c = 0; c < 10; c++){
    e0 = fmaf(o2[c], w3c[c*2+0], e0);
    e1 = fmaf(o2[c], w3c[c*2+1], e1);
  }
  float mx = fmaxf(e0, e1);
  float a0 = e0 - mx, a1 = e1 - mx;
  float lse = logf(expf(a0) + expf(a1));
  float2 r; r.x = a0 - lse; r.y = a1 - lse;
  *reinterpret_cast<float2*>(out + (size_t)q*2) = r;
}

extern "C" void kernel_launch(void* const* d_in, const int* in_sizes, int n_in,
                              void* d_out, int out_size, void* d_ws, size_t ws_size,
                              hipStream_t stream) {
  const float* x   = (const float*)d_in[0];
  const float* w1a = (const float*)d_in[1];
  const float* b1a = (const float*)d_in[2];
  const float* w1b = (const float*)d_in[3];
  const float* b1b = (const float*)d_in[4];
  const float* w2  = (const float*)d_in[5];
  const float* b2  = (const float*)d_in[6];
  const float* w3a = (const float*)d_in[7];
  const float* b3a = (const float*)d_in[8];
  const float* w3b = (const float*)d_in[9];
  const float* b3b = (const float*)d_in[10];
  const float* w3c = (const float*)d_in[11];
  const float* b3c = (const float*)d_in[12];
  float* out = (float*)d_out;

  char* ws = (char*)d_ws;
  float* cand = (float*)ws;                                        // NSPLIT*KNN*NQ fp32 (21.0 MB)
  float* x1r  = (float*)(ws + (size_t)NQ*NSPLIT*KNN*4);            // NQ*GFN fp32 (13.1 MB)
  float* pool = (float*)(ws + (size_t)NQ*NSPLIT*KNN*4
                            + (size_t)NQ*GFN*4);                   // NBATCH*GFN fp32

  knn_kernel<<<dim3(NQ/1024, NSPLIT), 256, 0, stream>>>(x, cand, pool);
  mlp1_kernel<<<NQ/MBLK, 512, 0, stream>>>(x, cand, w1a, b1a, w1b, b1b, w2, b2, x1r, pool);
  head_kernel<<<NQ/128, 128, 0, stream>>>(x1r, pool, w3a, b3a, w3b, b3b, w3c, b3c, out);
}

// Round 9
// 285.181 us; speedup vs baseline: 1.3256x; 1.0270x over previous
//
#include <hip/hip_runtime.h>
#include <math.h>

#define N_PTS   8192
#define NBATCH  4
#define NQ      (N_PTS*NBATCH)   // 32768
#define GFN     100
#define KNN     10
#define NSPLIT  16
#define SPLITL  (N_PTS/NSPLIT)   // 512
#define QPL     4                // queries per lane in knn
#define MBLK    128              // points per mlp1 block
#define WROW    112              // padded weight row: 4 chunks * 28 floats

__device__ __forceinline__ float med3f(float a, float b, float c){
  return __builtin_amdgcn_fmed3f(a, b, c);
}

// sorted insert of d into ascending m[0..9], dropping the largest. no-op if d>=m[9].
__device__ __forceinline__ void insert10(float (&m)[KNN], float d){
  #pragma unroll
  for (int k = KNN-1; k > 0; k--) m[k] = med3f(d, m[k-1], m[k]);
  m[0] = fminf(m[0], d);
}

__device__ __forceinline__ void ld7(float4 (&w)[7], const float* base){
  const float4* v = reinterpret_cast<const float4*>(base);
  #pragma unroll
  for (int i = 0; i < 7; i++) w[i] = v[i];
}

__device__ __forceinline__ void fma25(float (&acc)[25], float xv, const float4 (&w)[7]){
  #pragma unroll
  for (int i = 0; i < 6; i++){
    acc[i*4+0] = fmaf(xv, w[i].x, acc[i*4+0]);
    acc[i*4+1] = fmaf(xv, w[i].y, acc[i*4+1]);
    acc[i*4+2] = fmaf(xv, w[i].z, acc[i*4+2]);
    acc[i*4+3] = fmaf(xv, w[i].w, acc[i*4+3]);
  }
  acc[24] = fmaf(xv, w[6].x, acc[24]);
}

// ---------------- K0: repack weights (aligned padded chunks) + zero pool ----------------
__global__ __launch_bounds__(256) void prep_kernel(const float* __restrict__ w1b,
                                                   const float* __restrict__ w2,
                                                   float* __restrict__ w1bp,
                                                   float* __restrict__ w2p,
                                                   float* __restrict__ pool){
  const int t0 = blockIdx.x * 256 + threadIdx.x;
  const int stride = gridDim.x * 256;
  for (int i = t0; i < 20*WROW; i += stride){
    int c = i / WROW, j = i % WROW, ch = j / 28, k = j % 28;
    w1bp[i] = (k < 25) ? w1b[c*GFN + ch*25 + k] : 0.0f;
  }
  for (int i = t0; i < GFN*WROW; i += stride){
    int c = i / WROW, j = i % WROW, ch = j / 28, k = j % 28;
    w2p[i] = (k < 25) ? w2[c*GFN + ch*25 + k] : 0.0f;
  }
  for (int i = t0; i < NBATCH*GFN; i += stride) pool[i] = 0.0f;
}

// ---------------- K1: KNN top-10, 16-way split, 4 queries/lane (unchanged) ----------------
__global__ __launch_bounds__(256) void knn_kernel(const float* __restrict__ x,
                                                  float* __restrict__ cand){
  __shared__ float4 tile[SPLITL];   // 8 KB
  const int t   = threadIdx.x;
  const int w   = t >> 6;
  const int p   = t & 63;
  const int s   = blockIdx.y;       // 0..15
  const int qb0 = blockIdx.x * 1024;
  const int b   = qb0 >> 13;
  const float* xb = x + (size_t)b * N_PTS * 3;

  #pragma unroll
  for (int k = 0; k < 2; k++){
    const int j = t + 256*k;
    const float* ps = xb + (size_t)(s*SPLITL + j)*3;
    float px = ps[0], py = ps[1], pz = ps[2];
    tile[j] = make_float4(px, py, pz, fmaf(pz, pz, fmaf(py, py, px*px)));
  }
  __syncthreads();

  float qx[QPL], qy[QPL], qz[QPL], qs[QPL];
  #pragma unroll
  for (int u = 0; u < QPL; u++){
    const int q = qb0 + w*256 + u*64 + p;
    qx[u] = x[(size_t)q*3+0];
    qy[u] = x[(size_t)q*3+1];
    qz[u] = x[(size_t)q*3+2];
    qs[u] = fmaf(qz[u], qz[u], fmaf(qy[u], qy[u], qx[u]*qx[u]));
  }

  float m[QPL][KNN];
  #pragma unroll
  for (int u = 0; u < QPL; u++)
    #pragma unroll
    for (int k = 0; k < KNN; k++) m[u][k] = INFINITY;

  #pragma unroll 4
  for (int j = 0; j < SPLITL; j++){
    float4 pt = tile[j];
    #pragma unroll
    for (int u = 0; u < QPL; u++){
      float dot = fmaf(qz[u], pt.z, fmaf(qy[u], pt.y, qx[u]*pt.x));
      float d   = fmaf(-2.0f, dot, qs[u] + pt.w);
      insert10(m[u], d);
    }
  }

  #pragma unroll
  for (int u = 0; u < QPL; u++){
    const int q = qb0 + w*256 + u*64 + p;
    #pragma unroll
    for (int k = 0; k < KNN; k++) cand[(size_t)(s*KNN + k)*NQ + q] = m[u][k];
  }
}

// ------------- K2: merge, conv1 (13->20->100), conv2 (100->100) + pool -------------
// 512 threads = 8 waves, 128 points. Phase A: wave g (half=g>>2, sub=g&3) merges
// cand lists [sub*40,sub*40+40) for its half's 64 points -> LDS partials; wave
// sub==0 merges 4 partials + computes 13->20. Phases B/C: chunk=sub, 25 channels,
// weights via 7 aligned float4 loads per c (prep-packed), 2-deep dbuf in C.
__global__ __launch_bounds__(512) void mlp1_kernel(
    const float* __restrict__ x,    const float* __restrict__ cand,
    const float* __restrict__ w1a,  const float* __restrict__ b1a,
    const float* __restrict__ w1bp, const float* __restrict__ b1b,
    const float* __restrict__ w2p,  const float* __restrict__ b2,
    float* __restrict__ x1r, float* __restrict__ pool){
  __shared__ float t20s[MBLK*21];    // 10.75 KB
  __shared__ float x1s[MBLK*101];    // 51.7 KB (phase A aliases it for partials)
  const int t = threadIdx.x;
  const int p = t & 63;
  const int g = __builtin_amdgcn_readfirstlane(t >> 6);  // 0..7
  const int half = g >> 2;
  const int sub  = g & 3;
  const int ph = half*64 + p;        // point row in block
  const int q0 = blockIdx.x * MBLK;
  const int q  = q0 + ph;
  const int b  = q0 >> 13;

  // ---- phase A: split-list merge ----
  float* pa = x1s;                   // [8][64][11] partial top-10s (5632 floats)
  {
    float m[KNN];
    #pragma unroll
    for (int k = 0; k < KNN; k++) m[k] = INFINITY;
    const int i0 = sub*40;
    #pragma unroll 8
    for (int i = i0; i < i0+40; i++) insert10(m, cand[(size_t)i*NQ + q]);
    #pragma unroll
    for (int k = 0; k < KNN; k++) pa[(g*64+p)*11 + k] = m[k];
  }
  __syncthreads();

  if (sub == 0){
    float mm[KNN];
    #pragma unroll
    for (int k = 0; k < KNN; k++) mm[k] = pa[(g*64+p)*11 + k];   // own partial (sub 0)
    #pragma unroll
    for (int s2 = 1; s2 < 4; s2++)
      #pragma unroll
      for (int k = 0; k < KNN; k++)
        insert10(mm, pa[((half*4+s2)*64+p)*11 + k]);

    float h[13];
    h[0] = x[(size_t)q*3+0]; h[1] = x[(size_t)q*3+1]; h[2] = x[(size_t)q*3+2];
    #pragma unroll
    for (int k = 0; k < KNN; k++) h[3+k] = mm[k];

    float a[20];
    #pragma unroll
    for (int o = 0; o < 20; o++) a[o] = b1a[o];
    #pragma unroll
    for (int c = 0; c < 13; c++){
      float hv = h[c];
      #pragma unroll
      for (int o = 0; o < 20; o++) a[o] = fmaf(hv, w1a[c*20+o], a[o]);
    }
    #pragma unroll
    for (int o = 0; o < 20; o++) t20s[ph*21 + o] = fmaxf(a[o], 0.0f);
  }
  __syncthreads();

  const int o0 = sub * 25;
  float acc[25];

  // ---- phase B: x1 = relu(t20 @ w1b + b1b) ----
  #pragma unroll
  for (int k = 0; k < 25; k++) acc[k] = b1b[o0+k];
  #pragma unroll 2
  for (int c = 0; c < 20; c++){
    float tv = t20s[ph*21 + c];
    float4 wv[7];
    ld7(wv, w1bp + c*WROW + sub*28);
    fma25(acc, tv, wv);
  }
  #pragma unroll
  for (int k = 0; k < 25; k++){
    float v = fmaxf(acc[k], 0.0f);
    x1s[ph*101 + o0 + k] = v;
    x1r[(size_t)q*GFN + o0 + k] = v;
  }
  __syncthreads();

  // ---- phase C: x2 = relu(x1 @ w2 + b2), 2-deep weight dbuf ----
  #pragma unroll
  for (int k = 0; k < 25; k++) acc[k] = b2[o0+k];
  {
    float4 A[7], Bv[7];
    ld7(A, w2p + 0*WROW + sub*28);
    #pragma unroll 1
    for (int c = 0; c < GFN; c += 2){
      ld7(Bv, w2p + (c+1)*WROW + sub*28);
      float xv = x1s[ph*101 + c];
      fma25(acc, xv, A);
      if (c + 2 < GFN) ld7(A, w2p + (c+2)*WROW + sub*28);
      float xv2 = x1s[ph*101 + c + 1];
      fma25(acc, xv2, Bv);
    }
  }
  #pragma unroll
  for (int k = 0; k < 25; k++){
    float v = fmaxf(acc[k], 0.0f);
    #pragma unroll
    for (int off = 1; off < 64; off <<= 1) v += __shfl_xor(v, off);
    if (p == 0) atomicAdd(&pool[b*GFN + o0 + k], v);
  }
}

// ---------------- K3: head (200->20->10->2) + log_softmax ----------------
__global__ __launch_bounds__(128) void head_kernel(
    const float* __restrict__ x1r, const float* __restrict__ pool,
    const float* __restrict__ w3a, const float* __restrict__ b3a,
    const float* __restrict__ w3b, const float* __restrict__ b3b,
    const float* __restrict__ w3c, const float* __restrict__ b3c,
    float* __restrict__ out){
  __shared__ float poolm[GFN];
  __shared__ float poolpart[20];
  const int t = threadIdx.x;
  const int q = blockIdx.x * 128 + t;
  const int b = q >> 13;

  if (t < GFN) poolm[t] = pool[b*GFN+t] * (1.0f / (float)N_PTS);
  __syncthreads();
  if (t < 20){
    float a = b3a[t];
    for (int c = 0; c < GFN; c++) a = fmaf(poolm[c], w3a[(GFN+c)*20+t], a);
    poolpart[t] = a;
  }
  __syncthreads();

  float acc[20];
  #pragma unroll
  for (int o = 0; o < 20; o++) acc[o] = 0.0f;
  const float4* xr = reinterpret_cast<const float4*>(x1r + (size_t)q*GFN);
  #pragma unroll 5
  for (int c4 = 0; c4 < 25; c4++){
    float4 v = xr[c4];
    const float* wr = w3a + c4*4*20;
    #pragma unroll
    for (int o = 0; o < 20; o++) acc[o] = fmaf(v.x, wr[o],    acc[o]);
    #pragma unroll
    for (int o = 0; o < 20; o++) acc[o] = fmaf(v.y, wr[20+o], acc[o]);
    #pragma unroll
    for (int o = 0; o < 20; o++) acc[o] = fmaf(v.z, wr[40+o], acc[o]);
    #pragma unroll
    for (int o = 0; o < 20; o++) acc[o] = fmaf(v.w, wr[60+o], acc[o]);
  }
  float o1[20];
  #pragma unroll
  for (int o = 0; o < 20; o++) o1[o] = fmaxf(acc[o] + poolpart[o], 0.0f);

  float o2[10];
  #pragma unroll
  for (int o = 0; o < 10; o++){
    float a = b3b[o];
    #pragma unroll
    for (int c = 0; c < 20; c++) a = fmaf(o1[c], w3b[c*10+o], a);
    o2[o] = fmaxf(a, 0.0f);
  }
  float e0 = b3c[0], e1 = b3c[1];
  #pragma unroll
  for (int c = 0; c < 10; c++){
    e0 = fmaf(o2[c], w3c[c*2+0], e0);
    e1 = fmaf(o2[c], w3c[c*2+1], e1);
  }
  float mx = fmaxf(e0, e1);
  float a0 = e0 - mx, a1 = e1 - mx;
  float lse = logf(expf(a0) + expf(a1));
  float2 r; r.x = a0 - lse; r.y = a1 - lse;
  *reinterpret_cast<float2*>(out + (size_t)q*2) = r;
}

extern "C" void kernel_launch(void* const* d_in, const int* in_sizes, int n_in,
                              void* d_out, int out_size, void* d_ws, size_t ws_size,
                              hipStream_t stream) {
  const float* x   = (const float*)d_in[0];
  const float* w1a = (const float*)d_in[1];
  const float* b1a = (const float*)d_in[2];
  const float* w1b = (const float*)d_in[3];
  const float* b1b = (const float*)d_in[4];
  const float* w2  = (const float*)d_in[5];
  const float* b2  = (const float*)d_in[6];
  const float* w3a = (const float*)d_in[7];
  const float* b3a = (const float*)d_in[8];
  const float* w3b = (const float*)d_in[9];
  const float* b3b = (const float*)d_in[10];
  const float* w3c = (const float*)d_in[11];
  const float* b3c = (const float*)d_in[12];
  float* out = (float*)d_out;

  char* ws = (char*)d_ws;
  size_t off = 0;
  float* cand = (float*)(ws + off); off += (size_t)NQ*NSPLIT*KNN*4;   // 21.0 MB
  float* x1r  = (float*)(ws + off); off += (size_t)NQ*GFN*4;          // 13.1 MB
  float* pool = (float*)(ws + off); off += 4096;                      // 1.6 KB (padded)
  float* w1bp = (float*)(ws + off); off += (size_t)20*WROW*4;         // 9 KB (16B-aligned)
  float* w2p  = (float*)(ws + off); off += (size_t)GFN*WROW*4;        // 44.8 KB

  prep_kernel<<<16, 256, 0, stream>>>(w1b, w2, w1bp, w2p, pool);
  knn_kernel<<<dim3(NQ/1024, NSPLIT), 256, 0, stream>>>(x, cand);
  mlp1_kernel<<<NQ/MBLK, 512, 0, stream>>>(x, cand, w1a, b1a, w1bp, b1b, w2p, b2, x1r, pool);
  head_kernel<<<NQ/128, 128, 0, stream>>>(x1r, pool, w3a, b3a, w3b, b3b, w3c, b3c, out);
}